// Round 1
// baseline (3084.074 us; speedup 1.0000x reference)
//
#include <hip/hip_runtime.h>
#include <math.h>

// ---------------------------------------------------------------------------
// RefEncoder: 4x stride-2 conv encoder (fp32, direct conv) + per-group VQ head
// Shapes: x[16,3,256,256] -> c1[16,64,128,128] -> c2[16,128,64,64]
//         -> c3[16,256,32,32] -> latent[16,256,16,16]
// head: q = latent(grouped) @ wq ; kproj = codebook @ wk ; argmax(q @ kproj^T)
// Output (int32): 16384 codes [n,hh,ww,m] + tail [256,256]
// ---------------------------------------------------------------------------

__device__ __forceinline__ float gelu_tanh(float x) {
    // jax.nn.gelu(approximate=True)
    float x3 = x * x * x;
    return 0.5f * x * (1.0f + tanhf(0.7978845608028654f * (x + 0.044715f * x3)));
}

// Direct conv, stride 2, pad (0,1): iy = oy*2+ky, ix = ox*2+kx; valid if < Hi/Wi.
// One thread computes COPT consecutive output channels at one (n,oy,ox).
template <int Ci, int Co, int Hi, int Wi, int COPT, bool DO_GELU, bool NORM_IN>
__global__ void conv_s2_kernel(const float* __restrict__ in,
                               const float* __restrict__ w,
                               const float* __restrict__ b,
                               float* __restrict__ out, int N) {
    constexpr int Ho = Hi / 2, Wo = Wi / 2;
    constexpr int CG = Co / COPT;
    int gid = blockIdx.x * blockDim.x + threadIdx.x;
    int total = N * CG * Ho * Wo;
    if (gid >= total) return;
    int ox = gid % Wo;
    int oy = (gid / Wo) % Ho;
    int cg = (gid / (Wo * Ho)) % CG;
    int n  = gid / (Wo * Ho * CG);
    const int co0 = cg * COPT;

    float acc[COPT];
#pragma unroll
    for (int j = 0; j < COPT; ++j) acc[j] = 0.0f;

    for (int ci = 0; ci < Ci; ++ci) {
        const float* inp = in + (size_t)(n * Ci + ci) * Hi * Wi;
        const float* wp  = w + (size_t)(co0 * Ci + ci) * 9;
#pragma unroll
        for (int ky = 0; ky < 3; ++ky) {
            int iy = oy * 2 + ky;
            if (iy >= Hi) continue;
#pragma unroll
            for (int kx = 0; kx < 3; ++kx) {
                int ix = ox * 2 + kx;
                if (ix >= Wi) continue;
                float v = inp[(size_t)iy * Wi + ix];
                if (NORM_IN) v = 2.0f * v - 1.0f;  // (x-0.5)/0.5
#pragma unroll
                for (int j = 0; j < COPT; ++j)
                    acc[j] += v * wp[(size_t)j * Ci * 9 + ky * 3 + kx];
            }
        }
    }
#pragma unroll
    for (int j = 0; j < COPT; ++j) {
        float r = acc[j] + b[co0 + j];
        if (DO_GELU) r = gelu_tanh(r);
        out[(((size_t)n * Co + co0 + j) * Ho + oy) * Wo + ox] = r;
    }
}

// kproj[m][k][c] = sum_d codebook[m][k][d] * wk[m][c][d]
__global__ void kproj_kernel(const float* __restrict__ cb,
                             const float* __restrict__ wk,
                             float* __restrict__ kp) {
    int m = blockIdx.x >> 8;        // /256
    int k = blockIdx.x & 255;
    int c = threadIdx.x;            // 0..63
    const float* cbp = cb + (size_t)(m * 256 + k) * 64;
    const float* wkp = wk + (size_t)(m * 64 + c) * 64;
    float acc = 0.0f;
#pragma unroll 8
    for (int d = 0; d < 64; ++d) acc += cbp[d] * wkp[d];
    kp[(size_t)(m * 256 + k) * 64 + c] = acc;
}

// One block (256 threads) per latent pixel (n,hh,ww). Wave m handles group m.
__global__ void head_kernel(const float* __restrict__ latent,
                            const float* __restrict__ wq,
                            const float* __restrict__ kp,
                            int* __restrict__ out) {
    __shared__ float lat[256];
    __shared__ float q[256];
    int t = threadIdx.x;
    int pix = blockIdx.x;                 // (n*16+hh)*16+ww
    int wx = pix & 15, hh = (pix >> 4) & 15, n = pix >> 8;

    // latent layout [n][256][16][16]
    lat[t] = latent[(((size_t)n * 256 + t) * 16 + hh) * 16 + wx];
    __syncthreads();

    int m = t >> 6, c = t & 63;
    // q[m][c] = sum_d lat[m*64+d] * wq[m][c][d]
    const float* wqp = wq + (size_t)(m * 64 + c) * 64;
    float acc = 0.0f;
#pragma unroll 8
    for (int d = 0; d < 64; ++d) acc += lat[m * 64 + d] * wqp[d];
    q[t] = acc;
    __syncthreads();

    // Each lane scores keys {c, c+64, c+128, c+192} for group m.
    float best = -INFINITY;
    int bestk = 0;
    for (int j = 0; j < 4; ++j) {
        int k = j * 64 + c;
        const float* kpp = kp + (size_t)(m * 256 + k) * 64;
        float s = 0.0f;
#pragma unroll 8
        for (int d = 0; d < 64; ++d) s += q[m * 64 + d] * kpp[d];
        if (s > best) { best = s; bestk = k; }   // ascending k: strict > keeps lowest
    }
    // wave-64 reduce, tie-break lowest index (matches jnp.argmax first-max)
    for (int off = 32; off > 0; off >>= 1) {
        float s2 = __shfl_down(best, off, 64);
        int   k2 = __shfl_down(bestk, off, 64);
        if (s2 > best || (s2 == best && k2 < bestk)) { best = s2; bestk = k2; }
    }
    if (c == 0) out[pix * 4 + m] = bestk;
    if (pix == 0 && t == 0) { out[16384] = 256; out[16385] = 256; }
}

extern "C" void kernel_launch(void* const* d_in, const int* in_sizes, int n_in,
                              void* d_out, int out_size, void* d_ws, size_t ws_size,
                              hipStream_t stream) {
    const float* x  = (const float*)d_in[0];
    const float* w1 = (const float*)d_in[1];  const float* b1 = (const float*)d_in[2];
    const float* w2 = (const float*)d_in[3];  const float* b2 = (const float*)d_in[4];
    const float* w3 = (const float*)d_in[5];  const float* b3 = (const float*)d_in[6];
    const float* w4 = (const float*)d_in[7];  const float* b4 = (const float*)d_in[8];
    const float* cb = (const float*)d_in[9];
    const float* wq = (const float*)d_in[10];
    const float* wk = (const float*)d_in[11];
    int* out = (int*)d_out;

    const int N = 16;
    float* buf1 = (float*)d_ws;                               // 16*64*128*128
    float* buf2 = buf1 + (size_t)16 * 64 * 128 * 128;         // 16*128*64*64
    float* buf3 = buf2 + (size_t)16 * 128 * 64 * 64;          // 16*256*32*32
    float* buf4 = buf3 + (size_t)16 * 256 * 32 * 32;          // 16*256*16*16
    float* kp   = buf4 + (size_t)16 * 256 * 16 * 16;          // 4*256*64

    {   // conv1: 3->64, 256->128, COPT=4, norm in, gelu out
        int total = N * (64 / 4) * 128 * 128;
        conv_s2_kernel<3, 64, 256, 256, 4, true, true>
            <<<(total + 255) / 256, 256, 0, stream>>>(x, w1, b1, buf1, N);
    }
    {   // conv2: 64->128, 128->64, COPT=8, gelu
        int total = N * (128 / 8) * 64 * 64;
        conv_s2_kernel<64, 128, 128, 128, 8, true, false>
            <<<(total + 255) / 256, 256, 0, stream>>>(buf1, w2, b2, buf2, N);
    }
    {   // conv3: 128->256, 64->32, COPT=8, gelu
        int total = N * (256 / 8) * 32 * 32;
        conv_s2_kernel<128, 256, 64, 64, 8, true, false>
            <<<(total + 255) / 256, 256, 0, stream>>>(buf2, w3, b3, buf3, N);
    }
    {   // conv4: 256->256, 32->16, COPT=8, no gelu
        int total = N * (256 / 8) * 16 * 16;
        conv_s2_kernel<256, 256, 32, 32, 8, false, false>
            <<<(total + 255) / 256, 256, 0, stream>>>(buf3, w4, b4, buf4, N);
    }
    kproj_kernel<<<4 * 256, 64, 0, stream>>>(cb, wk, kp);
    head_kernel<<<16 * 16 * 16, 256, 0, stream>>>(buf4, wq, kp, out);
}

// Round 2
// 1268.913 us; speedup vs baseline: 2.4305x; 2.4305x over previous
//
#include <hip/hip_runtime.h>
#include <math.h>

// ---------------------------------------------------------------------------
// RefEncoder: 4x stride-2 conv encoder (fp32, tiled direct conv) + VQ head
// conv tiling: block=256 threads (16x16), each thread COPT chans x PY*PX pix,
// weights staged in LDS per ci-chunk (broadcast reads), 2x2 pixel microtile
// shares a 5x5 input window -> 288 FMA per 25 loads per ci.
// Output (int32): 16384 codes [n,hh,ww,m] + tail [256,256]
// ---------------------------------------------------------------------------

__device__ __forceinline__ float gelu_tanh(float x) {
    float x3 = x * x * x;
    return 0.5f * x * (1.0f + tanhf(0.7978845608028654f * (x + 0.044715f * x3)));
}

template <int Ci, int Co, int Hi, int Wi, int COPT, int PY, int PX, int CC,
          bool DO_GELU, bool NORM_IN>
__launch_bounds__(256)
__global__ void conv_tile_kernel(const float* __restrict__ in,
                                 const float* __restrict__ w,
                                 const float* __restrict__ bias,
                                 float* __restrict__ out, int N) {
    constexpr int Ho = Hi / 2, Wo = Wi / 2;
    constexpr int TW = 16 * PX, TH = 16 * PY;       // block pixel tile
    constexpr int tilesX = Wo / TW, tilesY = Ho / TH;
    constexpr int CGc = Co / COPT;
    constexpr int IH = 2 * PY + 1, IW = 2 * PX + 1; // shared input window
    constexpr int WCHUNK = CC * 9 * COPT;

    __shared__ float lds_w[WCHUNK];

    int t = threadIdx.x;
    int tx = t & 15, ty = t >> 4;
    int bx = blockIdx.x;
    int tileX = bx % tilesX; bx /= tilesX;
    int tileY = bx % tilesY; bx /= tilesY;
    int cg = bx % CGc;
    int n = bx / CGc;
    const int co0 = cg * COPT;
    const int ox0 = tileX * TW + tx * PX;
    const int oy0 = tileY * TH + ty * PY;

    float acc[COPT][PY * PX];
#pragma unroll
    for (int j = 0; j < COPT; ++j)
#pragma unroll
        for (int p = 0; p < PY * PX; ++p) acc[j][p] = 0.0f;

    for (int ci0 = 0; ci0 < Ci; ci0 += CC) {
        __syncthreads();
        for (int e = t; e < WCHUNK; e += 256) {
            int j = e % COPT;
            int tap = (e / COPT) % 9;
            int cl = e / (COPT * 9);
            lds_w[e] = w[((size_t)(co0 + j) * Ci + ci0 + cl) * 9 + tap];
        }
        __syncthreads();

#pragma unroll 2
        for (int cl = 0; cl < CC; ++cl) {
            const float* inp = in + ((size_t)n * Ci + ci0 + cl) * Hi * Wi;
            float v[IH][IW];
#pragma unroll
            for (int dy = 0; dy < IH; ++dy) {
                int iy = 2 * oy0 + dy;
#pragma unroll
                for (int dx = 0; dx < IW; ++dx) {
                    int ix = 2 * ox0 + dx;
                    float val = 0.0f;
                    if (iy < Hi && ix < Wi) {
                        val = inp[(size_t)iy * Wi + ix];
                        if (NORM_IN) val = 2.0f * val - 1.0f;  // pad stays 0
                    }
                    v[dy][dx] = val;
                }
            }
            const float* wp = lds_w + cl * 9 * COPT;
#pragma unroll
            for (int ky = 0; ky < 3; ++ky)
#pragma unroll
                for (int kx = 0; kx < 3; ++kx) {
                    const float* wt = wp + (ky * 3 + kx) * COPT;
#pragma unroll
                    for (int j = 0; j < COPT; ++j) {
                        float wj = wt[j];
#pragma unroll
                        for (int py = 0; py < PY; ++py)
#pragma unroll
                            for (int px = 0; px < PX; ++px)
                                acc[j][py * PX + px] +=
                                    v[2 * py + ky][2 * px + kx] * wj;
                    }
                }
        }
    }

#pragma unroll
    for (int j = 0; j < COPT; ++j) {
        float bj = bias[co0 + j];
#pragma unroll
        for (int py = 0; py < PY; ++py) {
            int oy = oy0 + py;
#pragma unroll
            for (int px = 0; px < PX; ++px) {
                int ox = ox0 + px;
                float r = acc[j][py * PX + px] + bj;
                if (DO_GELU) r = gelu_tanh(r);
                out[(((size_t)n * Co + co0 + j) * Ho + oy) * Wo + ox] = r;
            }
        }
    }
}

// kproj[m][k][c] = sum_d codebook[m][k][d] * wk[m][c][d]
__global__ void kproj_kernel(const float* __restrict__ cb,
                             const float* __restrict__ wk,
                             float* __restrict__ kp) {
    int m = blockIdx.x >> 8;
    int k = blockIdx.x & 255;
    int c = threadIdx.x;
    const float* cbp = cb + (size_t)(m * 256 + k) * 64;
    const float* wkp = wk + (size_t)(m * 64 + c) * 64;
    float acc = 0.0f;
#pragma unroll 8
    for (int d = 0; d < 64; ++d) acc += cbp[d] * wkp[d];
    kp[(size_t)(m * 256 + k) * 64 + c] = acc;
}

// One block (256 threads) per latent pixel (n,hh,ww). Wave m handles group m.
__global__ void head_kernel(const float* __restrict__ latent,
                            const float* __restrict__ wq,
                            const float* __restrict__ kp,
                            int* __restrict__ out) {
    __shared__ float lat[256];
    __shared__ float q[256];
    int t = threadIdx.x;
    int pix = blockIdx.x;
    int wx = pix & 15, hh = (pix >> 4) & 15, n = pix >> 8;

    lat[t] = latent[(((size_t)n * 256 + t) * 16 + hh) * 16 + wx];
    __syncthreads();

    int m = t >> 6, c = t & 63;
    const float* wqp = wq + (size_t)(m * 64 + c) * 64;
    float acc = 0.0f;
#pragma unroll 8
    for (int d = 0; d < 64; ++d) acc += lat[m * 64 + d] * wqp[d];
    q[t] = acc;
    __syncthreads();

    float best = -INFINITY;
    int bestk = 0;
    for (int j = 0; j < 4; ++j) {
        int k = j * 64 + c;
        const float* kpp = kp + (size_t)(m * 256 + k) * 64;
        float s = 0.0f;
#pragma unroll 8
        for (int d = 0; d < 64; ++d) s += q[m * 64 + d] * kpp[d];
        if (s > best) { best = s; bestk = k; }
    }
    for (int off = 32; off > 0; off >>= 1) {
        float s2 = __shfl_down(best, off, 64);
        int   k2 = __shfl_down(bestk, off, 64);
        if (s2 > best || (s2 == best && k2 < bestk)) { best = s2; bestk = k2; }
    }
    if (c == 0) out[pix * 4 + m] = bestk;
    if (pix == 0 && t == 0) { out[16384] = 256; out[16385] = 256; }
}

extern "C" void kernel_launch(void* const* d_in, const int* in_sizes, int n_in,
                              void* d_out, int out_size, void* d_ws, size_t ws_size,
                              hipStream_t stream) {
    const float* x  = (const float*)d_in[0];
    const float* w1 = (const float*)d_in[1];  const float* b1 = (const float*)d_in[2];
    const float* w2 = (const float*)d_in[3];  const float* b2 = (const float*)d_in[4];
    const float* w3 = (const float*)d_in[5];  const float* b3 = (const float*)d_in[6];
    const float* w4 = (const float*)d_in[7];  const float* b4 = (const float*)d_in[8];
    const float* cb = (const float*)d_in[9];
    const float* wq = (const float*)d_in[10];
    const float* wk = (const float*)d_in[11];
    int* out = (int*)d_out;

    const int N = 16;
    float* buf1 = (float*)d_ws;                               // 16*64*128*128
    float* buf2 = buf1 + (size_t)16 * 64 * 128 * 128;         // 16*128*64*64
    float* buf3 = buf2 + (size_t)16 * 128 * 64 * 64;          // 16*256*32*32
    float* buf4 = buf3 + (size_t)16 * 256 * 32 * 32;          // 16*256*16*16
    float* kp   = buf4 + (size_t)16 * 256 * 16 * 16;          // 4*256*64

    // conv1: 3->64, 256->256 in, tile 32x32, COPT=8, CC=3 (whole Ci)
    {
        int grid = N * (64 / 8) * (128 / 32) * (128 / 32);    // 2048
        conv_tile_kernel<3, 64, 256, 256, 8, 2, 2, 3, true, true>
            <<<grid, 256, 0, stream>>>(x, w1, b1, buf1, N);
    }
    // conv2: 64->128, tile 32x32, COPT=8, CC=16
    {
        int grid = N * (128 / 8) * (64 / 32) * (64 / 32);     // 1024
        conv_tile_kernel<64, 128, 128, 128, 8, 2, 2, 16, true, false>
            <<<grid, 256, 0, stream>>>(buf1, w2, b2, buf2, N);
    }
    // conv3: 128->256, tile 32x32 (whole plane), COPT=8, CC=16
    {
        int grid = N * (256 / 8) * (32 / 32) * (32 / 32);     // 512
        conv_tile_kernel<128, 256, 64, 64, 8, 2, 2, 16, true, false>
            <<<grid, 256, 0, stream>>>(buf2, w3, b3, buf3, N);
    }
    // conv4: 256->256, tile 16x16 (whole plane), COPT=16, PY=PX=1, CC=8
    {
        int grid = N * (256 / 16) * (16 / 16) * (16 / 16);    // 256
        conv_tile_kernel<256, 256, 32, 32, 16, 1, 1, 8, false, false>
            <<<grid, 256, 0, stream>>>(buf3, w4, b4, buf4, N);
    }
    kproj_kernel<<<4 * 256, 64, 0, stream>>>(cb, wk, kp);
    head_kernel<<<16 * 16 * 16, 256, 0, stream>>>(buf4, wq, kp, out);
}